// Round 6
// baseline (720.320 us; speedup 1.0000x reference)
//
#include <hip/hip_runtime.h>
#include <math.h>

typedef __attribute__((ext_vector_type(8))) short short8;   // 8 bf16 = 4 VGPR
typedef __attribute__((ext_vector_type(4))) float f32x4;

__device__ inline unsigned short f2bf(float f) {
    unsigned int u = __float_as_uint(f);
    u += 0x7fffu + ((u >> 16) & 1u);          // RNE
    return (unsigned short)(u >> 16);
}
__device__ inline float bf2f(unsigned int h) { return __uint_as_float(h << 16); }

#define GLOAD_LDS16(gp, lp)                                                              \
    __builtin_amdgcn_global_load_lds(                                                    \
        (const __attribute__((address_space(1))) unsigned int*)(const void*)(gp),        \
        (__attribute__((address_space(3))) unsigned int*)(void*)(lp), 16, 0, 0)

// ---------------- degree / CSR ----------------

__global__ void init_k(float* deg, int* cnt, int N) {
    int i = blockIdx.x * blockDim.x + threadIdx.x;
    if (i < N) { deg[i] = 1.0f; cnt[i] = 0; }
}

__global__ void deg_cnt_k(const int* __restrict__ dst, const float* __restrict__ w,
                          float* deg, int* cnt, int E) {
    int e = blockIdx.x * blockDim.x + threadIdx.x;
    if (e < E) { int d = dst[e]; atomicAdd(&deg[d], w[e]); atomicAdd(&cnt[d], 1); }
}

__global__ void dinv_k(float* deg, int N) {
    int i = blockIdx.x * blockDim.x + threadIdx.x;
    if (i < N) { float d = deg[i]; deg[i] = d > 0.f ? rsqrtf(d) : 0.f; }
}

__global__ void scan_k(const int* __restrict__ cnt, int* __restrict__ rp,
                       int* __restrict__ ofs, int N) {
    __shared__ int buf[2][1024];
    __shared__ int carry_s;
    int tid = threadIdx.x;
    if (tid == 0) { carry_s = 0; rp[0] = 0; }
    __syncthreads();
    for (int base = 0; base < N; base += 1024) {
        int i = base + tid;
        int v = (i < N) ? cnt[i] : 0;
        int pp = 0;
        buf[0][tid] = v;
        __syncthreads();
        for (int o = 1; o < 1024; o <<= 1) {
            int nv = buf[pp][tid];
            if (tid >= o) nv += buf[pp][tid - o];
            buf[pp ^ 1][tid] = nv;
            pp ^= 1;
            __syncthreads();
        }
        int inc = buf[pp][tid];
        int c = carry_s;
        if (i < N) { rp[i + 1] = c + inc; ofs[i] = c + inc - v; }
        __syncthreads();
        if (tid == 1023) carry_s = c + inc;
        __syncthreads();
    }
}

__global__ void fill_csr_k(const int* __restrict__ src, const int* __restrict__ dst,
                           const float* __restrict__ w, const float* __restrict__ dinv,
                           int* ofs, int* __restrict__ csr_src, float* __restrict__ csr_norm, int E) {
    int e = blockIdx.x * blockDim.x + threadIdx.x;
    if (e < E) {
        int s = src[e], d = dst[e];
        int p = atomicAdd(&ofs[d], 1);
        csr_src[p] = s;
        csr_norm[p] = dinv[s] * w[e] * dinv[d];
    }
}

// ---------------- conversions ----------------

__global__ void cvt_x_k(const float* __restrict__ x, unsigned short* __restrict__ zx, int N) {
    int t = blockIdx.x * blockDim.x + threadIdx.x;
    if (t >= N * 32) return;
    int r = t >> 5, c4 = (t & 31) * 4;
    float4 v = *(const float4*)&x[(size_t)r * 128 + c4];
    uint2 o;
    o.x = (unsigned)f2bf(v.x) | ((unsigned)f2bf(v.y) << 16);
    o.y = (unsigned)f2bf(v.z) | ((unsigned)f2bf(v.w) << 16);
    *(uint2*)&zx[(size_t)r * 256 + 128 + c4] = o;
}

__global__ void cvt_ph_k(const float* __restrict__ ph, unsigned short* __restrict__ d, int N) {
    int t = blockIdx.x * blockDim.x + threadIdx.x;
    if (t >= N * 64) return;
    int r = t >> 6, c4 = (t & 63) * 4;
    float4 v = *(const float4*)&ph[(size_t)r * 256 + c4];
    uint2 o;
    o.x = (unsigned)f2bf(v.x) | ((unsigned)f2bf(v.y) << 16);
    o.y = (unsigned)f2bf(v.z) | ((unsigned)f2bf(v.w) << 16);
    *(uint2*)&d[(size_t)r * 256 + c4] = o;
}

// all weights -> bf16, transposed to Bt[n][k]
__global__ void cvtw_k(const float* W1, const float* W2,
                       const float* Wxz, const float* Whz, const float* Wxr, const float* Whr,
                       const float* Wxh, const float* Whh,
                       unsigned short* Bt1, unsigned short* Bt2,
                       unsigned short* BtZR, unsigned short* BtH) {
    int t = blockIdx.x * blockDim.x + threadIdx.x;
    if (t < 32768) { int k = t >> 8, n = t & 255; Bt1[(size_t)n * 128 + k] = f2bf(W1[t]); return; }
    t -= 32768;
    if (t < 32768) { int k = t >> 7, n = t & 127; Bt2[(size_t)n * 256 + k] = f2bf(W2[t]); return; }
    t -= 32768;
    if (t < 65536) { int k = t >> 8, n = t & 255; BtZR[(size_t)n * 512 + k] = f2bf(Wxz[t]); return; }
    t -= 65536;
    if (t < 65536) { int k = t >> 8, n = t & 255; BtZR[(size_t)n * 512 + 256 + k] = f2bf(Whz[t]); return; }
    t -= 65536;
    if (t < 65536) { int k = t >> 8, n = t & 255; BtZR[(size_t)(256 + n) * 512 + k] = f2bf(Wxr[t]); return; }
    t -= 65536;
    if (t < 65536) { int k = t >> 8, n = t & 255; BtZR[(size_t)(256 + n) * 512 + 256 + k] = f2bf(Whr[t]); return; }
    t -= 65536;
    if (t < 65536) { int k = t >> 8, n = t & 255; BtH[(size_t)n * 512 + k] = f2bf(Wxh[t]); return; }
    t -= 65536;
    if (t < 65536) { int k = t >> 8, n = t & 255; BtH[(size_t)n * 512 + 256 + k] = f2bf(Whh[t]); }
}

__global__ void bias_fuse_k(const float* bxz, const float* bhz, const float* bxr, const float* bhr,
                            const float* bxh, const float* bhh, float* bZR, float* bH) {
    int t = blockIdx.x * blockDim.x + threadIdx.x;
    if (t < 256)       bZR[t] = bxz[t] + bhz[t];
    else if (t < 512)  bZR[t] = bxr[t - 256] + bhr[t - 256];
    else if (t < 768)  bH[t - 512] = bxh[t - 512] + bhh[t - 512];
}

// ---------------- CSR gather (bf16 in, f32 accum, bf16 out) ----------------
template <int EPI>
__global__ void agg_bf_k(const int* __restrict__ rp, const int* __restrict__ cs,
                         const float* __restrict__ cn,
                         const unsigned short* __restrict__ X, int ldx2, int xo2,
                         const float* __restrict__ dinv, const float* __restrict__ bias,
                         unsigned short* __restrict__ Y, int ldy2, int yo2, int N) {
    int wid = (blockIdx.x * blockDim.x + threadIdx.x) >> 6;
    int lane = threadIdx.x & 63;
    if (wid >= N) return;
    const unsigned int* Xu = (const unsigned int*)X;
    float dv = dinv[wid]; dv *= dv;
    unsigned int sv = Xu[(size_t)wid * ldx2 + xo2 + lane];
    float ax = bf2f(sv & 0xffffu) * dv, ay = bf2f(sv >> 16) * dv;
    int p = rp[wid], pe = rp[wid + 1];
    for (; p + 4 <= pe; p += 4) {
        int s0 = cs[p], s1 = cs[p+1], s2 = cs[p+2], s3 = cs[p+3];
        float n0 = cn[p], n1 = cn[p+1], n2 = cn[p+2], n3 = cn[p+3];
        unsigned int v0 = Xu[(size_t)s0 * ldx2 + xo2 + lane];
        unsigned int v1 = Xu[(size_t)s1 * ldx2 + xo2 + lane];
        unsigned int v2 = Xu[(size_t)s2 * ldx2 + xo2 + lane];
        unsigned int v3 = Xu[(size_t)s3 * ldx2 + xo2 + lane];
        ax = fmaf(bf2f(v0 & 0xffffu), n0, ax); ay = fmaf(bf2f(v0 >> 16), n0, ay);
        ax = fmaf(bf2f(v1 & 0xffffu), n1, ax); ay = fmaf(bf2f(v1 >> 16), n1, ay);
        ax = fmaf(bf2f(v2 & 0xffffu), n2, ax); ay = fmaf(bf2f(v2 >> 16), n2, ay);
        ax = fmaf(bf2f(v3 & 0xffffu), n3, ax); ay = fmaf(bf2f(v3 >> 16), n3, ay);
    }
    for (; p < pe; ++p) {
        int s = cs[p]; float nv = cn[p];
        unsigned int v = Xu[(size_t)s * ldx2 + xo2 + lane];
        ax = fmaf(bf2f(v & 0xffffu), nv, ax); ay = fmaf(bf2f(v >> 16), nv, ay);
    }
    if (EPI == 1) {
        ax = fmaxf(ax + bias[lane * 2], 0.f);
        ay = fmaxf(ay + bias[lane * 2 + 1], 0.f);
    }
    unsigned int o = (unsigned)f2bf(ax) | ((unsigned)f2bf(ay) << 16);
    ((unsigned int*)Y)[(size_t)wid * ldy2 + yo2 + lane] = o;
}

// ---------------- head ----------------

__global__ void colsum_bf_k(const unsigned short* __restrict__ Z, float* zsum, int N) {
    int c = threadIdx.x;
    int rpb = (N + gridDim.x - 1) / gridDim.x;
    int r0 = blockIdx.x * rpb, r1 = min(N, r0 + rpb);
    float s = 0.f;
    for (int r = r0; r < r1; ++r) s += bf2f((unsigned int)Z[(size_t)r * 256 + c]);
    atomicAdd(&zsum[c], s);
}

__global__ void head_k(const float* __restrict__ zsum, const float* __restrict__ Wh,
                       const float* __restrict__ bh, float* __restrict__ out, float invN) {
    __shared__ float red[128];
    int c = threadIdx.x;
    red[c] = zsum[c] * invN * Wh[c];
    __syncthreads();
    for (int s = 64; s > 0; s >>= 1) {
        if (c < s) red[c] += red[c + s];
        __syncthreads();
    }
    if (c == 0) out[0] = red[0] + bh[0];
}

// ---------------- bf16 MFMA GEMM, 128x128 tile (real, unchanged from r5) ----------------

enum { EPI_G = 0, EPI_P = 1, EPI_ZR = 2, EPI_H = 3 };

__global__ __launch_bounds__(256)
void mm_bf16_k(const unsigned short* __restrict__ A0, const unsigned short* __restrict__ A1,
               int lda0, int lda1, int kb,
               const unsigned short* __restrict__ Bt, int K, int M, int ncb,
               const float* __restrict__ bias,
               const unsigned short* __restrict__ xb1, const unsigned short* __restrict__ xb2,
               void* __restrict__ out, void* __restrict__ out2, int epi)
{
    __shared__ unsigned short Als[2][4096];
    __shared__ unsigned short Bls[2][4096];

    int nwg = gridDim.x;
    int bid = blockIdx.x;
    int q = nwg >> 3, r = nwg & 7;
    int xcd = bid & 7;
    int wg = (xcd < r ? xcd * (q + 1) : r * (q + 1) + (xcd - r) * q) + (bid >> 3);
    int brow = wg / ncb, bcol = wg - brow * ncb;
    int row0 = brow * 128, col0 = bcol * 128;

    int t = threadIdx.x;
    int w = t >> 6, lane = t & 63;
    int wr = w >> 1, wc = w & 1;
    int m15 = lane & 15, g = lane >> 4;

    int srow = lane >> 2;
    int skk  = (((lane & 3) ^ ((lane >> 3) & 3)) << 3);

    f32x4 acc[4][4];
    #pragma unroll
    for (int i = 0; i < 4; ++i)
        #pragma unroll
        for (int j = 0; j < 4; ++j)
            #pragma unroll
            for (int qq = 0; qq < 4; ++qq) acc[i][j][qq] = 0.f;

    auto stage = [&](int buf, int kt) {
        const unsigned short* Ap = A0; int lda = lda0; int ka = kt;
        if (kt >= kb) { Ap = A1; lda = lda1; ka = kt - kb; }
        #pragma unroll
        for (int i = 0; i < 2; ++i) {
            int chunk = i * 4 + w;
            int arow = chunk * 16 + srow;
            int gr = row0 + arow; gr = gr < M ? gr : M - 1;
            GLOAD_LDS16(&Ap[(size_t)gr * lda + ka + skk], &Als[buf][chunk * 512]);
            GLOAD_LDS16(&Bt[(size_t)(col0 + arow) * K + kt + skk], &Bls[buf][chunk * 512]);
        }
    };

    int NT = K >> 5;
    stage(0, 0);
    int pb = 0;

    for (int ti = 0; ti < NT; ++ti) {
        if (ti + 1 < NT) {
            stage(pb ^ 1, (ti + 1) << 5);
            asm volatile("s_waitcnt vmcnt(4)" ::: "memory");
        } else {
            asm volatile("s_waitcnt vmcnt(0)" ::: "memory");
        }
        __builtin_amdgcn_s_barrier();
        __builtin_amdgcn_sched_barrier(0);

        short8 af[4], bfr[4];
        #pragma unroll
        for (int ms = 0; ms < 4; ++ms) {
            int rt = wr * 64 + ms * 16 + m15;
            af[ms] = *(const short8*)&Als[pb][rt * 32 + ((g ^ ((rt >> 1) & 3)) << 3)];
        }
        #pragma unroll
        for (int ns = 0; ns < 4; ++ns) {
            int nt = wc * 64 + ns * 16 + m15;
            bfr[ns] = *(const short8*)&Bls[pb][nt * 32 + ((g ^ ((nt >> 1) & 3)) << 3)];
        }
        asm volatile("s_waitcnt lgkmcnt(0)" ::: "memory");
        __builtin_amdgcn_sched_barrier(0);
        __builtin_amdgcn_s_barrier();

        #pragma unroll
        for (int ms = 0; ms < 4; ++ms)
            #pragma unroll
            for (int ns = 0; ns < 4; ++ns)
                acc[ms][ns] = __builtin_amdgcn_mfma_f32_16x16x32_bf16(af[ms], bfr[ns], acc[ms][ns], 0, 0, 0);
        pb ^= 1;
    }

    int r4 = (lane >> 4) * 4;
    #pragma unroll
    for (int ms = 0; ms < 4; ++ms) {
        #pragma unroll
        for (int ns = 0; ns < 4; ++ns) {
            int col = col0 + wc * 64 + ns * 16 + m15;
            #pragma unroll
            for (int i = 0; i < 4; ++i) {
                int row = row0 + wr * 64 + ms * 16 + r4 + i;
                if (row >= M) continue;
                float v = acc[ms][ns][i];
                if (epi == EPI_G) {
                    float val = fmaxf(v + bias[col], 0.f) + bf2f((unsigned)xb1[(size_t)row * 256 + col]);
                    ((unsigned short*)out)[(size_t)row * 256 + col] = f2bf(val);
                } else if (epi == EPI_P) {
                    ((unsigned short*)out)[(size_t)row * 128 + col] = f2bf(v);
                } else if (epi == EPI_ZR) {
                    float s = 1.f / (1.f + __expf(-(v + bias[col])));
                    if (col < 256) {
                        ((unsigned short*)out)[(size_t)row * 256 + col] = f2bf(s);
                    } else {
                        int c2 = col - 256;
                        ((unsigned short*)out2)[(size_t)row * 256 + c2] =
                            f2bf(bf2f((unsigned)xb1[(size_t)row * 256 + c2]) * s);
                    }
                } else {
                    float s = v + bias[col];
                    float e = __expf(2.f * s);
                    float ht = 1.f - 2.f / (e + 1.f);
                    float Zt = bf2f((unsigned)xb2[(size_t)row * 256 + col]);
                    float ph = bf2f((unsigned)xb1[(size_t)row * 256 + col]);
                    ((float*)out)[(size_t)row * 256 + col] = Zt * ph + (1.f - Zt) * ht;
                }
            }
        }
    }
}

// ---------------- DIAGNOSTIC variants (write only to ws scratch) ----------------
// MODE 1: staging + vmcnt + barrier rhythm only (no ds_read, no MFMA).
// MODE 3: full K-loop, but epilogue = coalesced float4 dump of reduced acc.

template <int MODE>
__global__ __launch_bounds__(256)
void mm_diag_k(const unsigned short* __restrict__ A0, const unsigned short* __restrict__ A1,
               int lda0, int lda1, int kb,
               const unsigned short* __restrict__ Bt, int K, int M, int ncb,
               float* __restrict__ diag)
{
    __shared__ unsigned short Als[2][4096];
    __shared__ unsigned short Bls[2][4096];

    int nwg = gridDim.x;
    int bid = blockIdx.x;
    int q = nwg >> 3, r = nwg & 7;
    int xcd = bid & 7;
    int wg = (xcd < r ? xcd * (q + 1) : r * (q + 1) + (xcd - r) * q) + (bid >> 3);
    int brow = wg / ncb, bcol = wg - brow * ncb;
    int row0 = brow * 128, col0 = bcol * 128;

    int t = threadIdx.x;
    int w = t >> 6, lane = t & 63;
    int wr = w >> 1, wc = w & 1;
    int m15 = lane & 15, g = lane >> 4;
    int srow = lane >> 2;
    int skk  = (((lane & 3) ^ ((lane >> 3) & 3)) << 3);

    f32x4 acc[4][4];
    if constexpr (MODE >= 2) {
        #pragma unroll
        for (int i = 0; i < 4; ++i)
            #pragma unroll
            for (int j = 0; j < 4; ++j)
                #pragma unroll
                for (int qq = 0; qq < 4; ++qq) acc[i][j][qq] = 0.f;
    }

    auto stage = [&](int buf, int kt) {
        const unsigned short* Ap = A0; int lda = lda0; int ka = kt;
        if (kt >= kb) { Ap = A1; lda = lda1; ka = kt - kb; }
        #pragma unroll
        for (int i = 0; i < 2; ++i) {
            int chunk = i * 4 + w;
            int arow = chunk * 16 + srow;
            int gr = row0 + arow; gr = gr < M ? gr : M - 1;
            GLOAD_LDS16(&Ap[(size_t)gr * lda + ka + skk], &Als[buf][chunk * 512]);
            GLOAD_LDS16(&Bt[(size_t)(col0 + arow) * K + kt + skk], &Bls[buf][chunk * 512]);
        }
    };

    int NT = K >> 5;
    stage(0, 0);
    int pb = 0;

    for (int ti = 0; ti < NT; ++ti) {
        if (ti + 1 < NT) {
            stage(pb ^ 1, (ti + 1) << 5);
            asm volatile("s_waitcnt vmcnt(4)" ::: "memory");
        } else {
            asm volatile("s_waitcnt vmcnt(0)" ::: "memory");
        }
        __builtin_amdgcn_s_barrier();
        __builtin_amdgcn_sched_barrier(0);

        if constexpr (MODE >= 2) {
            short8 af[4], bfr[4];
            #pragma unroll
            for (int ms = 0; ms < 4; ++ms) {
                int rt = wr * 64 + ms * 16 + m15;
                af[ms] = *(const short8*)&Als[pb][rt * 32 + ((g ^ ((rt >> 1) & 3)) << 3)];
            }
            #pragma unroll
            for (int ns = 0; ns < 4; ++ns) {
                int nt = wc * 64 + ns * 16 + m15;
                bfr[ns] = *(const short8*)&Bls[pb][nt * 32 + ((g ^ ((nt >> 1) & 3)) << 3)];
            }
            asm volatile("s_waitcnt lgkmcnt(0)" ::: "memory");
            __builtin_amdgcn_sched_barrier(0);
            __builtin_amdgcn_s_barrier();
            #pragma unroll
            for (int ms = 0; ms < 4; ++ms)
                #pragma unroll
                for (int ns = 0; ns < 4; ++ns)
                    acc[ms][ns] = __builtin_amdgcn_mfma_f32_16x16x32_bf16(af[ms], bfr[ns], acc[ms][ns], 0, 0, 0);
        } else {
            __builtin_amdgcn_s_barrier();   // keep 2-barrier rhythm
        }
        pb ^= 1;
    }

    if constexpr (MODE == 1) {
        // keep staging observable; one coalesced u32 per thread
        unsigned v = *(const unsigned*)&Als[0][t * 2];
        ((unsigned*)diag)[(size_t)blockIdx.x * 256 + t] = v;
    } else {
        f32x4 s = acc[0][0];
        #pragma unroll
        for (int ms = 0; ms < 4; ++ms)
            #pragma unroll
            for (int ns = 0; ns < 4; ++ns)
                if (ms || ns) {
                    s[0] += acc[ms][ns][0]; s[1] += acc[ms][ns][1];
                    s[2] += acc[ms][ns][2]; s[3] += acc[ms][ns][3];
                }
        *(f32x4*)&diag[((size_t)blockIdx.x * 256 + t) * 4] = s;
    }
}

// ---------------- launch ----------------

extern "C" void kernel_launch(void* const* d_in, const int* in_sizes, int n_in,
                              void* d_out, int out_size, void* d_ws, size_t ws_size,
                              hipStream_t stream) {
    const float* x      = (const float*)d_in[0];
    const int*   ei     = (const int*)d_in[1];
    const float* ew     = (const float*)d_in[2];
    const float* prev_h = (const float*)d_in[3];
    const float* W1  = (const float*)d_in[4];  const float* b1  = (const float*)d_in[5];
    const float* W2  = (const float*)d_in[6];  const float* b2  = (const float*)d_in[7];
    const float* Wxz = (const float*)d_in[8];  const float* bxz = (const float*)d_in[9];
    const float* Whz = (const float*)d_in[10]; const float* bhz = (const float*)d_in[11];
    const float* Wxr = (const float*)d_in[12]; const float* bxr = (const float*)d_in[13];
    const float* Whr = (const float*)d_in[14]; const float* bhr = (const float*)d_in[15];
    const float* Wxh = (const float*)d_in[16]; const float* bxh = (const float*)d_in[17];
    const float* Whh = (const float*)d_in[18]; const float* bhh = (const float*)d_in[19];
    const float* Whead = (const float*)d_in[20]; const float* bhead = (const float*)d_in[21];

    const int N = in_sizes[0] / 128;
    const int E = in_sizes[2];
    const int* esrc = ei;
    const int* edst = ei + E;

    float* ws = (float*)d_ws;
    size_t o = 0;
    float* dinv     = ws + o; o += (size_t)N;
    int*   cnt      = (int*)(ws + o); o += (size_t)N;
    int*   rowp     = (int*)(ws + o); o += (size_t)N + 4;
    int*   csr_src  = (int*)(ws + o); o += (size_t)E;
    float* csr_norm = ws + o; o += (size_t)E;
    unsigned short* zx   = (unsigned short*)(ws + o); o += (size_t)N * 128;
    unsigned short* phb  = (unsigned short*)(ws + o); o += (size_t)N * 128;
    unsigned short* buf1 = (unsigned short*)(ws + o); o += (size_t)N * 128;
    unsigned short* Zbf  = (unsigned short*)(ws + o); o += (size_t)N * 128;
    unsigned short* Bt1  = (unsigned short*)(ws + o); o += 16384;
    unsigned short* Bt2  = (unsigned short*)(ws + o); o += 16384;
    unsigned short* BtZR = (unsigned short*)(ws + o); o += 131072;
    unsigned short* BtH  = (unsigned short*)(ws + o); o += 65536;
    float* bZR      = ws + o; o += 512;
    float* bH       = ws + o; o += 256;
    float* zsum     = ws + o; o += 128;
    float* diag     = ws + o; o += (size_t)(((N + 127) / 128) * 4) * 256 * 4;  // diag scratch

    unsigned short* g_bf = Zbf;
    float* hout = (float*)d_out + 1;

    const int TPB = 256;
    int gN = (N + TPB - 1) / TPB;
    int gE = (E + TPB - 1) / TPB;
    int gAgg = (N * 64 + TPB - 1) / TPB;
    int nb = (N + 127) / 128;

    // norm + CSR
    init_k<<<gN, TPB, 0, stream>>>(dinv, cnt, N);
    deg_cnt_k<<<gE, TPB, 0, stream>>>(edst, ew, dinv, cnt, E);
    dinv_k<<<gN, TPB, 0, stream>>>(dinv, N);
    scan_k<<<1, 1024, 0, stream>>>(cnt, rowp, cnt, N);
    fill_csr_k<<<gE, TPB, 0, stream>>>(esrc, edst, ew, dinv, cnt, csr_src, csr_norm, E);

    // conversions
    cvt_x_k<<<(N * 32 + TPB - 1) / TPB, TPB, 0, stream>>>(x, zx, N);
    cvt_ph_k<<<(N * 64 + TPB - 1) / TPB, TPB, 0, stream>>>(prev_h, phb, N);
    cvtw_k<<<1792, TPB, 0, stream>>>(W1, W2, Wxz, Whz, Wxr, Whr, Wxh, Whh, Bt1, Bt2, BtZR, BtH);
    bias_fuse_k<<<3, TPB, 0, stream>>>(bxz, bhz, bxr, bhr, bxh, bhh, bZR, bH);

    // t = agg(x)
    agg_bf_k<0><<<gAgg, TPB, 0, stream>>>(rowp, csr_src, csr_norm, zx, 128, 64, dinv,
                                          nullptr, buf1, 64, 0, N);

    // g = relu(t@W1 + b1) + prev_h
    mm_bf16_k<<<nb * 2, 256, 0, stream>>>(buf1, buf1, 128, 128, 128, Bt1, 128, N, 2,
                                          b1, phb, nullptr, g_bf, nullptr, EPI_G);
    // gw2 = g@W2
    mm_bf16_k<<<nb, 256, 0, stream>>>(g_bf, g_bf, 256, 256, 256, Bt2, 256, N, 1,
                                      nullptr, nullptr, nullptr, buf1, nullptr, EPI_P);
    // z = relu(agg(gw2) + b2)
    agg_bf_k<1><<<gAgg, TPB, 0, stream>>>(rowp, csr_src, csr_norm, buf1, 64, 0, dinv,
                                          b2, zx, 128, 0, N);

    // head
    hipMemsetAsync(zsum, 0, 128 * sizeof(float), stream);
    colsum_bf_k<<<512, 128, 0, stream>>>(zx, zsum, N);
    head_k<<<1, 128, 0, stream>>>(zsum, Whead, bhead, (float*)d_out, 1.0f / (float)N);

    // Z|R fused GEMM
    mm_bf16_k<<<nb * 4, 256, 0, stream>>>(zx, phb, 256, 256, 256, BtZR, 512, N, 4,
                                          bZR, phb, nullptr, Zbf, buf1, EPI_ZR);
    // h GEMM
    mm_bf16_k<<<nb * 2, 256, 0, stream>>>(zx, buf1, 256, 256, 256, BtH, 512, N, 2,
                                          bH, phb, Zbf, hout, nullptr, EPI_H);

    // ---- diagnostics (dead scratch writes; ZR-shaped) ----
    mm_diag_k<1><<<nb * 4, 256, 0, stream>>>(zx, phb, 256, 256, 256, BtZR, 512, N, 4, diag);
    mm_diag_k<3><<<nb * 4, 256, 0, stream>>>(zx, phb, 256, 256, 256, BtZR, 512, N, 4, diag);
}

// Round 7
// 551.013 us; speedup vs baseline: 1.3073x; 1.3073x over previous
//
#include <hip/hip_runtime.h>
#include <math.h>

typedef __attribute__((ext_vector_type(8))) short short8;   // 8 bf16 = 4 VGPR
typedef __attribute__((ext_vector_type(4))) float f32x4;

__device__ inline unsigned short f2bf(float f) {
    unsigned int u = __float_as_uint(f);
    u += 0x7fffu + ((u >> 16) & 1u);          // RNE
    return (unsigned short)(u >> 16);
}
__device__ inline float bf2f(unsigned int h) { return __uint_as_float(h << 16); }
__device__ inline unsigned pack2(float a, float b) {
    return (unsigned)f2bf(a) | ((unsigned)f2bf(b) << 16);
}

#define GLOAD_LDS16(gp, lp)                                                              \
    __builtin_amdgcn_global_load_lds(                                                    \
        (const __attribute__((address_space(1))) unsigned int*)(const void*)(gp),        \
        (__attribute__((address_space(3))) unsigned int*)(void*)(lp), 16, 0, 0)

// ---------------- degree / CSR ----------------

__global__ void init_k(float* deg, int* cnt, int N) {
    int i = blockIdx.x * blockDim.x + threadIdx.x;
    if (i < N) { deg[i] = 1.0f; cnt[i] = 0; }
}

__global__ void deg_cnt_k(const int* __restrict__ dst, const float* __restrict__ w,
                          float* deg, int* cnt, int E) {
    int e = blockIdx.x * blockDim.x + threadIdx.x;
    if (e < E) { int d = dst[e]; atomicAdd(&deg[d], w[e]); atomicAdd(&cnt[d], 1); }
}

__global__ void dinv_k(float* deg, int N) {
    int i = blockIdx.x * blockDim.x + threadIdx.x;
    if (i < N) { float d = deg[i]; deg[i] = d > 0.f ? rsqrtf(d) : 0.f; }
}

__global__ void scan_k(const int* __restrict__ cnt, int* __restrict__ rp,
                       int* __restrict__ ofs, int N) {
    __shared__ int buf[2][1024];
    __shared__ int carry_s;
    int tid = threadIdx.x;
    if (tid == 0) { carry_s = 0; rp[0] = 0; }
    __syncthreads();
    for (int base = 0; base < N; base += 1024) {
        int i = base + tid;
        int v = (i < N) ? cnt[i] : 0;
        int pp = 0;
        buf[0][tid] = v;
        __syncthreads();
        for (int o = 1; o < 1024; o <<= 1) {
            int nv = buf[pp][tid];
            if (tid >= o) nv += buf[pp][tid - o];
            buf[pp ^ 1][tid] = nv;
            pp ^= 1;
            __syncthreads();
        }
        int inc = buf[pp][tid];
        int c = carry_s;
        if (i < N) { rp[i + 1] = c + inc; ofs[i] = c + inc - v; }
        __syncthreads();
        if (tid == 1023) carry_s = c + inc;
        __syncthreads();
    }
}

__global__ void fill_csr_k(const int* __restrict__ src, const int* __restrict__ dst,
                           const float* __restrict__ w, const float* __restrict__ dinv,
                           int* ofs, int* __restrict__ csr_src, float* __restrict__ csr_norm, int E) {
    int e = blockIdx.x * blockDim.x + threadIdx.x;
    if (e < E) {
        int s = src[e], d = dst[e];
        int p = atomicAdd(&ofs[d], 1);
        csr_src[p] = s;
        csr_norm[p] = dinv[s] * w[e] * dinv[d];
    }
}

// ---------------- conversions ----------------

__global__ void cvt_x_k(const float* __restrict__ x, unsigned short* __restrict__ zx, int N) {
    int t = blockIdx.x * blockDim.x + threadIdx.x;
    if (t >= N * 32) return;
    int r = t >> 5, c4 = (t & 31) * 4;
    float4 v = *(const float4*)&x[(size_t)r * 128 + c4];
    uint2 o;
    o.x = pack2(v.x, v.y);
    o.y = pack2(v.z, v.w);
    *(uint2*)&zx[(size_t)r * 256 + 128 + c4] = o;
}

__global__ void cvt_ph_k(const float* __restrict__ ph, unsigned short* __restrict__ d, int N) {
    int t = blockIdx.x * blockDim.x + threadIdx.x;
    if (t >= N * 64) return;
    int r = t >> 6, c4 = (t & 63) * 4;
    float4 v = *(const float4*)&ph[(size_t)r * 256 + c4];
    uint2 o;
    o.x = pack2(v.x, v.y);
    o.y = pack2(v.z, v.w);
    *(uint2*)&d[(size_t)r * 256 + c4] = o;
}

// all weights -> bf16, transposed to Bt[n][k]
__global__ void cvtw_k(const float* W1, const float* W2,
                       const float* Wxz, const float* Whz, const float* Wxr, const float* Whr,
                       const float* Wxh, const float* Whh,
                       unsigned short* Bt1, unsigned short* Bt2,
                       unsigned short* BtZR, unsigned short* BtH) {
    int t = blockIdx.x * blockDim.x + threadIdx.x;
    if (t < 32768) { int k = t >> 8, n = t & 255; Bt1[(size_t)n * 128 + k] = f2bf(W1[t]); return; }
    t -= 32768;
    if (t < 32768) { int k = t >> 7, n = t & 127; Bt2[(size_t)n * 256 + k] = f2bf(W2[t]); return; }
    t -= 32768;
    if (t < 65536) { int k = t >> 8, n = t & 255; BtZR[(size_t)n * 512 + k] = f2bf(Wxz[t]); return; }
    t -= 65536;
    if (t < 65536) { int k = t >> 8, n = t & 255; BtZR[(size_t)n * 512 + 256 + k] = f2bf(Whz[t]); return; }
    t -= 65536;
    if (t < 65536) { int k = t >> 8, n = t & 255; BtZR[(size_t)(256 + n) * 512 + k] = f2bf(Wxr[t]); return; }
    t -= 65536;
    if (t < 65536) { int k = t >> 8, n = t & 255; BtZR[(size_t)(256 + n) * 512 + 256 + k] = f2bf(Whr[t]); return; }
    t -= 65536;
    if (t < 65536) { int k = t >> 8, n = t & 255; BtH[(size_t)n * 512 + k] = f2bf(Wxh[t]); return; }
    t -= 65536;
    if (t < 65536) { int k = t >> 8, n = t & 255; BtH[(size_t)n * 512 + 256 + k] = f2bf(Whh[t]); }
}

__global__ void bias_fuse_k(const float* bxz, const float* bhz, const float* bxr, const float* bhr,
                            const float* bxh, const float* bhh, float* bZR, float* bH) {
    int t = blockIdx.x * blockDim.x + threadIdx.x;
    if (t < 256)       bZR[t] = bxz[t] + bhz[t];
    else if (t < 512)  bZR[t] = bxr[t - 256] + bhr[t - 256];
    else if (t < 768)  bH[t - 512] = bxh[t - 512] + bhh[t - 512];
}

// ---------------- CSR gather (bf16 in, f32 accum, bf16 out) ----------------
template <int EPI>
__global__ void agg_bf_k(const int* __restrict__ rp, const int* __restrict__ cs,
                         const float* __restrict__ cn,
                         const unsigned short* __restrict__ X, int ldx2, int xo2,
                         const float* __restrict__ dinv, const float* __restrict__ bias,
                         unsigned short* __restrict__ Y, int ldy2, int yo2, int N) {
    int wid = (blockIdx.x * blockDim.x + threadIdx.x) >> 6;
    int lane = threadIdx.x & 63;
    if (wid >= N) return;
    const unsigned int* Xu = (const unsigned int*)X;
    float dv = dinv[wid]; dv *= dv;
    unsigned int sv = Xu[(size_t)wid * ldx2 + xo2 + lane];
    float ax = bf2f(sv & 0xffffu) * dv, ay = bf2f(sv >> 16) * dv;
    int p = rp[wid], pe = rp[wid + 1];
    for (; p + 4 <= pe; p += 4) {
        int s0 = cs[p], s1 = cs[p+1], s2 = cs[p+2], s3 = cs[p+3];
        float n0 = cn[p], n1 = cn[p+1], n2 = cn[p+2], n3 = cn[p+3];
        unsigned int v0 = Xu[(size_t)s0 * ldx2 + xo2 + lane];
        unsigned int v1 = Xu[(size_t)s1 * ldx2 + xo2 + lane];
        unsigned int v2 = Xu[(size_t)s2 * ldx2 + xo2 + lane];
        unsigned int v3 = Xu[(size_t)s3 * ldx2 + xo2 + lane];
        ax = fmaf(bf2f(v0 & 0xffffu), n0, ax); ay = fmaf(bf2f(v0 >> 16), n0, ay);
        ax = fmaf(bf2f(v1 & 0xffffu), n1, ax); ay = fmaf(bf2f(v1 >> 16), n1, ay);
        ax = fmaf(bf2f(v2 & 0xffffu), n2, ax); ay = fmaf(bf2f(v2 >> 16), n2, ay);
        ax = fmaf(bf2f(v3 & 0xffffu), n3, ax); ay = fmaf(bf2f(v3 >> 16), n3, ay);
    }
    for (; p < pe; ++p) {
        int s = cs[p]; float nv = cn[p];
        unsigned int v = Xu[(size_t)s * ldx2 + xo2 + lane];
        ax = fmaf(bf2f(v & 0xffffu), nv, ax); ay = fmaf(bf2f(v >> 16), nv, ay);
    }
    if (EPI == 1) {
        ax = fmaxf(ax + bias[lane * 2], 0.f);
        ay = fmaxf(ay + bias[lane * 2 + 1], 0.f);
    }
    ((unsigned int*)Y)[(size_t)wid * ldy2 + yo2 + lane] = pack2(ax, ay);
}

// ---------------- head ----------------

__global__ void colsum_bf_k(const unsigned short* __restrict__ Z, float* zsum, int N) {
    int c = threadIdx.x;
    int rpb = (N + gridDim.x - 1) / gridDim.x;
    int r0 = blockIdx.x * rpb, r1 = min(N, r0 + rpb);
    float s = 0.f;
    for (int r = r0; r < r1; ++r) s += bf2f((unsigned int)Z[(size_t)r * 256 + c]);
    atomicAdd(&zsum[c], s);
}

__global__ void head_k(const float* __restrict__ zsum, const float* __restrict__ Wh,
                       const float* __restrict__ bh, float* __restrict__ out, float invN) {
    __shared__ float red[128];
    int c = threadIdx.x;
    red[c] = zsum[c] * invN * Wh[c];
    __syncthreads();
    for (int s = 64; s > 0; s >>= 1) {
        if (c < s) red[c] += red[c + s];
        __syncthreads();
    }
    if (c == 0) out[0] = red[0] + bh[0];
}

// ---------------- bf16 MFMA GEMM, 128x128 tile, transposed-acc epilogue ----------------
// Operand-swap trick: mfma(bfr, af) computes C^T in the C/D layout, so each lane
// holds C[row = ...+lane&15][4 consecutive cols = ...+(lane>>4)*4 + reg].
// Epilogue then uses packed uint2 (4xbf16) / float4 accesses.

enum { EPI_G = 0, EPI_P = 1, EPI_ZR = 2, EPI_H = 3 };

__global__ __launch_bounds__(256)
void mm_bf16_k(const unsigned short* __restrict__ A0, const unsigned short* __restrict__ A1,
               int lda0, int lda1, int kb,
               const unsigned short* __restrict__ Bt, int K, int M, int ncb,
               const float* __restrict__ bias,
               const unsigned short* __restrict__ xb1, const unsigned short* __restrict__ xb2,
               void* __restrict__ out, void* __restrict__ out2, int epi)
{
    __shared__ unsigned short Als[2][4096];
    __shared__ unsigned short Bls[2][4096];

    // XCD-bijective swizzle, bcol fast
    int nwg = gridDim.x;
    int bid = blockIdx.x;
    int q = nwg >> 3, r = nwg & 7;
    int xcd = bid & 7;
    int wg = (xcd < r ? xcd * (q + 1) : r * (q + 1) + (xcd - r) * q) + (bid >> 3);
    int brow = wg / ncb, bcol = wg - brow * ncb;
    int row0 = brow * 128, col0 = bcol * 128;

    int t = threadIdx.x;
    int w = t >> 6, lane = t & 63;
    int wr = w >> 1, wc = w & 1;
    int m15 = lane & 15, g = lane >> 4;

    int srow = lane >> 2;
    int skk  = (((lane & 3) ^ ((lane >> 3) & 3)) << 3);

    f32x4 acc[4][4];
    #pragma unroll
    for (int i = 0; i < 4; ++i)
        #pragma unroll
        for (int j = 0; j < 4; ++j)
            #pragma unroll
            for (int qq = 0; qq < 4; ++qq) acc[i][j][qq] = 0.f;

    auto stage = [&](int buf, int kt) {
        const unsigned short* Ap = A0; int lda = lda0; int ka = kt;
        if (kt >= kb) { Ap = A1; lda = lda1; ka = kt - kb; }
        #pragma unroll
        for (int i = 0; i < 2; ++i) {
            int chunk = i * 4 + w;
            int arow = chunk * 16 + srow;
            int gr = row0 + arow; gr = gr < M ? gr : M - 1;
            GLOAD_LDS16(&Ap[(size_t)gr * lda + ka + skk], &Als[buf][chunk * 512]);
            GLOAD_LDS16(&Bt[(size_t)(col0 + arow) * K + kt + skk], &Bls[buf][chunk * 512]);
        }
    };

    int NT = K >> 5;
    stage(0, 0);
    int pb = 0;

    for (int ti = 0; ti < NT; ++ti) {
        if (ti + 1 < NT) {
            stage(pb ^ 1, (ti + 1) << 5);
            asm volatile("s_waitcnt vmcnt(4)" ::: "memory");
        } else {
            asm volatile("s_waitcnt vmcnt(0)" ::: "memory");
        }
        __builtin_amdgcn_s_barrier();
        __builtin_amdgcn_sched_barrier(0);

        short8 af[4], bfr[4];
        #pragma unroll
        for (int ms = 0; ms < 4; ++ms) {
            int rt = wr * 64 + ms * 16 + m15;
            af[ms] = *(const short8*)&Als[pb][rt * 32 + ((g ^ ((rt >> 1) & 3)) << 3)];
        }
        #pragma unroll
        for (int ns = 0; ns < 4; ++ns) {
            int nt = wc * 64 + ns * 16 + m15;
            bfr[ns] = *(const short8*)&Bls[pb][nt * 32 + ((g ^ ((nt >> 1) & 3)) << 3)];
        }
        asm volatile("s_waitcnt lgkmcnt(0)" ::: "memory");
        __builtin_amdgcn_sched_barrier(0);
        __builtin_amdgcn_s_barrier();

        #pragma unroll
        for (int ms = 0; ms < 4; ++ms)
            #pragma unroll
            for (int ns = 0; ns < 4; ++ns)
                acc[ms][ns] = __builtin_amdgcn_mfma_f32_16x16x32_bf16(bfr[ns], af[ms], acc[ms][ns], 0, 0, 0);
        pb ^= 1;
    }

    // epilogue: row = row0 + wr*64 + ms*16 + m15 ; cols = col0 + wc*64 + ns*16 + g*4 + (0..3)
    #pragma unroll
    for (int ms = 0; ms < 4; ++ms) {
        int row = row0 + wr * 64 + ms * 16 + m15;
        bool rok = row < M;
        #pragma unroll
        for (int ns = 0; ns < 4; ++ns) {
            int col = col0 + wc * 64 + ns * 16 + g * 4;
            f32x4 a = acc[ms][ns];
            if (epi == EPI_G) {
                float4 bv = *(const float4*)&bias[col];
                uint2 p4 = *(const uint2*)&xb1[(size_t)row * 256 + col];
                uint2 o;
                o.x = pack2(fmaxf(a[0] + bv.x, 0.f) + bf2f(p4.x & 0xffffu),
                            fmaxf(a[1] + bv.y, 0.f) + bf2f(p4.x >> 16));
                o.y = pack2(fmaxf(a[2] + bv.z, 0.f) + bf2f(p4.y & 0xffffu),
                            fmaxf(a[3] + bv.w, 0.f) + bf2f(p4.y >> 16));
                if (rok) *(uint2*)&((unsigned short*)out)[(size_t)row * 256 + col] = o;
            } else if (epi == EPI_P) {
                uint2 o;
                o.x = pack2(a[0], a[1]);
                o.y = pack2(a[2], a[3]);
                if (rok) *(uint2*)&((unsigned short*)out)[(size_t)row * 128 + col] = o;
            } else if (epi == EPI_ZR) {
                float4 bv = *(const float4*)&bias[col];
                float s0 = 1.f / (1.f + __expf(-(a[0] + bv.x)));
                float s1 = 1.f / (1.f + __expf(-(a[1] + bv.y)));
                float s2 = 1.f / (1.f + __expf(-(a[2] + bv.z)));
                float s3 = 1.f / (1.f + __expf(-(a[3] + bv.w)));
                if (col < 256) {
                    uint2 o; o.x = pack2(s0, s1); o.y = pack2(s2, s3);
                    if (rok) *(uint2*)&((unsigned short*)out)[(size_t)row * 256 + col] = o;
                } else {
                    int c2 = col - 256;
                    uint2 p4 = *(const uint2*)&xb1[(size_t)row * 256 + c2];
                    uint2 o;
                    o.x = pack2(bf2f(p4.x & 0xffffu) * s0, bf2f(p4.x >> 16) * s1);
                    o.y = pack2(bf2f(p4.y & 0xffffu) * s2, bf2f(p4.y >> 16) * s3);
                    if (rok) *(uint2*)&((unsigned short*)out2)[(size_t)row * 256 + c2] = o;
                }
            } else {  // EPI_H
                float4 bv = *(const float4*)&bias[col];
                uint2 z4 = *(const uint2*)&xb2[(size_t)row * 256 + col];
                uint2 p4 = *(const uint2*)&xb1[(size_t)row * 256 + col];
                float4 o;
                {
                    float s = a[0] + bv.x, e = __expf(2.f * s);
                    float ht = 1.f - 2.f / (e + 1.f);
                    float Zt = bf2f(z4.x & 0xffffu), ph = bf2f(p4.x & 0xffffu);
                    o.x = Zt * ph + (1.f - Zt) * ht;
                }
                {
                    float s = a[1] + bv.y, e = __expf(2.f * s);
                    float ht = 1.f - 2.f / (e + 1.f);
                    float Zt = bf2f(z4.x >> 16), ph = bf2f(p4.x >> 16);
                    o.y = Zt * ph + (1.f - Zt) * ht;
                }
                {
                    float s = a[2] + bv.z, e = __expf(2.f * s);
                    float ht = 1.f - 2.f / (e + 1.f);
                    float Zt = bf2f(z4.y & 0xffffu), ph = bf2f(p4.y & 0xffffu);
                    o.z = Zt * ph + (1.f - Zt) * ht;
                }
                {
                    float s = a[3] + bv.w, e = __expf(2.f * s);
                    float ht = 1.f - 2.f / (e + 1.f);
                    float Zt = bf2f(z4.y >> 16), ph = bf2f(p4.y >> 16);
                    o.w = Zt * ph + (1.f - Zt) * ht;
                }
                if (rok) *(float4*)&((float*)out)[(size_t)row * 256 + col] = o;
            }
        }
    }
}

// ---------------- launch ----------------

extern "C" void kernel_launch(void* const* d_in, const int* in_sizes, int n_in,
                              void* d_out, int out_size, void* d_ws, size_t ws_size,
                              hipStream_t stream) {
    const float* x      = (const float*)d_in[0];
    const int*   ei     = (const int*)d_in[1];
    const float* ew     = (const float*)d_in[2];
    const float* prev_h = (const float*)d_in[3];
    const float* W1  = (const float*)d_in[4];  const float* b1  = (const float*)d_in[5];
    const float* W2  = (const float*)d_in[6];  const float* b2  = (const float*)d_in[7];
    const float* Wxz = (const float*)d_in[8];  const float* bxz = (const float*)d_in[9];
    const float* Whz = (const float*)d_in[10]; const float* bhz = (const float*)d_in[11];
    const float* Wxr = (const float*)d_in[12]; const float* bxr = (const float*)d_in[13];
    const float* Whr = (const float*)d_in[14]; const float* bhr = (const float*)d_in[15];
    const float* Wxh = (const float*)d_in[16]; const float* bxh = (const float*)d_in[17];
    const float* Whh = (const float*)d_in[18]; const float* bhh = (const float*)d_in[19];
    const float* Whead = (const float*)d_in[20]; const float* bhead = (const float*)d_in[21];

    const int N = in_sizes[0] / 128;
    const int E = in_sizes[2];
    const int* esrc = ei;
    const int* edst = ei + E;

    float* ws = (float*)d_ws;
    size_t o = 0;
    float* dinv     = ws + o; o += (size_t)N;
    int*   cnt      = (int*)(ws + o); o += (size_t)N;
    int*   rowp     = (int*)(ws + o); o += (size_t)N + 4;
    int*   csr_src  = (int*)(ws + o); o += (size_t)E;
    float* csr_norm = ws + o; o += (size_t)E;
    unsigned short* zx   = (unsigned short*)(ws + o); o += (size_t)N * 128;  // [N,256]: z | x
    unsigned short* phb  = (unsigned short*)(ws + o); o += (size_t)N * 128;  // prev_h bf16
    unsigned short* buf1 = (unsigned short*)(ws + o); o += (size_t)N * 128;  // t -> gw2 -> q
    unsigned short* Zbf  = (unsigned short*)(ws + o); o += (size_t)N * 128;  // g_bf -> Z bf16
    unsigned short* Bt1  = (unsigned short*)(ws + o); o += 16384;
    unsigned short* Bt2  = (unsigned short*)(ws + o); o += 16384;
    unsigned short* BtZR = (unsigned short*)(ws + o); o += 131072;
    unsigned short* BtH  = (unsigned short*)(ws + o); o += 65536;
    float* bZR      = ws + o; o += 512;
    float* bH       = ws + o; o += 256;
    float* zsum     = ws + o; o += 128;

    unsigned short* g_bf = Zbf;
    float* hout = (float*)d_out + 1;

    const int TPB = 256;
    int gN = (N + TPB - 1) / TPB;
    int gE = (E + TPB - 1) / TPB;
    int gAgg = (N * 64 + TPB - 1) / TPB;
    int nb = (N + 127) / 128;

    // norm + CSR
    init_k<<<gN, TPB, 0, stream>>>(dinv, cnt, N);
    deg_cnt_k<<<gE, TPB, 0, stream>>>(edst, ew, dinv, cnt, E);
    dinv_k<<<gN, TPB, 0, stream>>>(dinv, N);
    scan_k<<<1, 1024, 0, stream>>>(cnt, rowp, cnt, N);
    fill_csr_k<<<gE, TPB, 0, stream>>>(esrc, edst, ew, dinv, cnt, csr_src, csr_norm, E);

    // conversions
    cvt_x_k<<<(N * 32 + TPB - 1) / TPB, TPB, 0, stream>>>(x, zx, N);
    cvt_ph_k<<<(N * 64 + TPB - 1) / TPB, TPB, 0, stream>>>(prev_h, phb, N);
    cvtw_k<<<1792, TPB, 0, stream>>>(W1, W2, Wxz, Whz, Wxr, Whr, Wxh, Whh, Bt1, Bt2, BtZR, BtH);
    bias_fuse_k<<<3, TPB, 0, stream>>>(bxz, bhz, bxr, bhr, bxh, bhh, bZR, bH);

    // t = agg(x)
    agg_bf_k<0><<<gAgg, TPB, 0, stream>>>(rowp, csr_src, csr_norm, zx, 128, 64, dinv,
                                          nullptr, buf1, 64, 0, N);

    // g = relu(t@W1 + b1) + prev_h
    mm_bf16_k<<<nb * 2, 256, 0, stream>>>(buf1, buf1, 128, 128, 128, Bt1, 128, N, 2,
                                          b1, phb, nullptr, g_bf, nullptr, EPI_G);
    // gw2 = g@W2
    mm_bf16_k<<<nb, 256, 0, stream>>>(g_bf, g_bf, 256, 256, 256, Bt2, 256, N, 1,
                                      nullptr, nullptr, nullptr, buf1, nullptr, EPI_P);
    // z = relu(agg(gw2) + b2)
    agg_bf_k<1><<<gAgg, TPB, 0, stream>>>(rowp, csr_src, csr_norm, buf1, 64, 0, dinv,
                                          b2, zx, 128, 0, N);

    // head
    hipMemsetAsync(zsum, 0, 128 * sizeof(float), stream);
    colsum_bf_k<<<512, 128, 0, stream>>>(zx, zsum, N);
    head_k<<<1, 128, 0, stream>>>(zsum, Whead, bhead, (float*)d_out, 1.0f / (float)N);

    // Z|R fused GEMM
    mm_bf16_k<<<nb * 4, 256, 0, stream>>>(zx, phb, 256, 256, 256, BtZR, 512, N, 4,
                                          bZR, phb, nullptr, Zbf, buf1, EPI_ZR);
    // h GEMM
    mm_bf16_k<<<nb * 2, 256, 0, stream>>>(zx, buf1, 256, 256, 256, BtH, 512, N, 2,
                                          bH, phb, Zbf, hout, nullptr, EPI_H);
}

// Round 9
// 462.386 us; speedup vs baseline: 1.5578x; 1.1917x over previous
//
#include <hip/hip_runtime.h>
#include <math.h>

typedef __attribute__((ext_vector_type(8))) short short8;   // 8 bf16 = 4 VGPR
typedef __attribute__((ext_vector_type(4))) float f32x4;

__device__ inline unsigned short f2bf(float f) {
    unsigned int u = __float_as_uint(f);
    u += 0x7fffu + ((u >> 16) & 1u);          // RNE
    return (unsigned short)(u >> 16);
}
__device__ inline float bf2f(unsigned int h) { return __uint_as_float(h << 16); }
__device__ inline unsigned pack2(float a, float b) {
    return (unsigned)f2bf(a) | ((unsigned)f2bf(b) << 16);
}

#define GLOAD_LDS16(gp, lp)                                                              \
    __builtin_amdgcn_global_load_lds(                                                    \
        (const __attribute__((address_space(1))) unsigned int*)(const void*)(gp),        \
        (__attribute__((address_space(3))) unsigned int*)(void*)(lp), 16, 0, 0)

// ---------------- fused prep: deg/cnt init + x->bf16 + prev_h->bf16 ----------------

__global__ void prep_k(const float* __restrict__ x, const float* __restrict__ ph,
                       float* __restrict__ deg, int* __restrict__ cnt,
                       unsigned short* __restrict__ zx, unsigned short* __restrict__ phb, int N) {
    int t = blockIdx.x * blockDim.x + threadIdx.x;
    if (t < N) { deg[t] = 1.0f; cnt[t] = 0; return; }
    t -= N;
    if (t < N * 32) {           // cvt_x -> zx cols 128..255
        int r = t >> 5, c4 = (t & 31) * 4;
        float4 v = *(const float4*)&x[(size_t)r * 128 + c4];
        uint2 o; o.x = pack2(v.x, v.y); o.y = pack2(v.z, v.w);
        *(uint2*)&zx[(size_t)r * 256 + 128 + c4] = o;
        return;
    }
    t -= N * 32;
    if (t < N * 64) {           // cvt_ph
        int r = t >> 6, c4 = (t & 63) * 4;
        float4 v = *(const float4*)&ph[(size_t)r * 256 + c4];
        uint2 o; o.x = pack2(v.x, v.y); o.y = pack2(v.z, v.w);
        *(uint2*)&phb[(size_t)r * 256 + c4] = o;
    }
}

// ---------------- weights -> bf16 transposed + fused biases ----------------
// thread space: 32768 (W1) + 32768 (W2) + 6*65536 (Wxz,Whz,Wxr,Whr,Wxh,Whh) + 768 (biases)

__global__ void cvtwb_k(const float* W1, const float* W2,
                        const float* Wxz, const float* Whz, const float* Wxr, const float* Whr,
                        const float* Wxh, const float* Whh,
                        const float* bxz, const float* bhz, const float* bxr, const float* bhr,
                        const float* bxh, const float* bhh,
                        unsigned short* Bt1, unsigned short* Bt2,
                        unsigned short* BtZR, unsigned short* BtH,
                        float* bZR, float* bH) {
    int t = blockIdx.x * blockDim.x + threadIdx.x;
    if (t < 32768) { int k = t >> 8, n = t & 255; Bt1[(size_t)n * 128 + k] = f2bf(W1[t]); return; }
    t -= 32768;
    if (t < 32768) { int k = t >> 7, n = t & 127; Bt2[(size_t)n * 256 + k] = f2bf(W2[t]); return; }
    t -= 32768;
    if (t < 65536) { int k = t >> 8, n = t & 255; BtZR[(size_t)n * 512 + k] = f2bf(Wxz[t]); return; }
    t -= 65536;
    if (t < 65536) { int k = t >> 8, n = t & 255; BtZR[(size_t)n * 512 + 256 + k] = f2bf(Whz[t]); return; }
    t -= 65536;
    if (t < 65536) { int k = t >> 8, n = t & 255; BtZR[(size_t)(256 + n) * 512 + k] = f2bf(Wxr[t]); return; }
    t -= 65536;
    if (t < 65536) { int k = t >> 8, n = t & 255; BtZR[(size_t)(256 + n) * 512 + 256 + k] = f2bf(Whr[t]); return; }
    t -= 65536;
    if (t < 65536) { int k = t >> 8, n = t & 255; BtH[(size_t)n * 512 + k] = f2bf(Wxh[t]); return; }
    t -= 65536;
    if (t < 65536) { int k = t >> 8, n = t & 255; BtH[(size_t)n * 512 + 256 + k] = f2bf(Whh[t]); return; }
    t -= 65536;
    if (t < 256)       bZR[t] = bxz[t] + bhz[t];
    else if (t < 512)  bZR[t] = bxr[t - 256] + bhr[t - 256];
    else if (t < 768)  bH[t - 512] = bxh[t - 512] + bhh[t - 512];
}

// ---------------- degree / CSR ----------------

__global__ void deg_cnt_k(const int* __restrict__ dst, const float* __restrict__ w,
                          float* deg, int* cnt, int E) {
    int e = blockIdx.x * blockDim.x + threadIdx.x;
    if (e < E) { int d = dst[e]; atomicAdd(&deg[d], w[e]); atomicAdd(&cnt[d], 1); }
}

__global__ void dinv_k(float* deg, int N) {
    int i = blockIdx.x * blockDim.x + threadIdx.x;
    if (i < N) { float d = deg[i]; deg[i] = d > 0.f ? rsqrtf(d) : 0.f; }
}

// hierarchical exclusive scan of cnt[0..N) -> rp[0..N], cnt becomes fill cursor
__global__ void scan1_k(const int* __restrict__ cnt, int* __restrict__ bsum, int N) {
    __shared__ int ws_[4];
    int b = blockIdx.x, t = threadIdx.x;
    int i = b * 256 + t;
    int v = (i < N) ? cnt[i] : 0;
    int lane = t & 63, wv = t >> 6;
    #pragma unroll
    for (int o = 1; o < 64; o <<= 1) { int u = __shfl_up(v, o, 64); if (lane >= o) v += u; }
    if (lane == 63) ws_[wv] = v;
    __syncthreads();
    if (t == 0) bsum[b] = ws_[0] + ws_[1] + ws_[2] + ws_[3];
}

__global__ void scan2_k(int* __restrict__ bsum, int nb) {
    __shared__ int ws_[4];
    int t = threadIdx.x;
    int v = (t < nb) ? bsum[t] : 0;
    int orig = v;
    int lane = t & 63, wv = t >> 6;
    #pragma unroll
    for (int o = 1; o < 64; o <<= 1) { int u = __shfl_up(v, o, 64); if (lane >= o) v += u; }
    if (lane == 63) ws_[wv] = v;
    __syncthreads();
    int add = 0;
    for (int k = 0; k < wv; ++k) add += ws_[k];
    if (t < nb) bsum[t] = v + add - orig;     // exclusive block offset
}

__global__ void scan3_k(int* __restrict__ cnt, const int* __restrict__ bsum,
                        int* __restrict__ rp, int N) {
    __shared__ int ws_[4];
    int b = blockIdx.x, t = threadIdx.x;
    int i = b * 256 + t;
    int v = (i < N) ? cnt[i] : 0;
    int orig = v;
    int lane = t & 63, wv = t >> 6;
    #pragma unroll
    for (int o = 1; o < 64; o <<= 1) { int u = __shfl_up(v, o, 64); if (lane >= o) v += u; }
    if (lane == 63) ws_[wv] = v;
    __syncthreads();
    int add = bsum[b];
    for (int k = 0; k < wv; ++k) add += ws_[k];
    int incl = v + add;
    if (i < N) {
        rp[i + 1] = incl;
        cnt[i] = incl - orig;                 // exclusive -> fill cursor
        if (i == 0) rp[0] = 0;
    }
}

__global__ void fill_csr_k(const int* __restrict__ src, const int* __restrict__ dst,
                           const float* __restrict__ w, const float* __restrict__ dinv,
                           int* ofs, int* __restrict__ csr_src, float* __restrict__ csr_norm, int E) {
    int e = blockIdx.x * blockDim.x + threadIdx.x;
    if (e < E) {
        int s = src[e], d = dst[e];
        int p = atomicAdd(&ofs[d], 1);
        csr_src[p] = s;
        csr_norm[p] = dinv[s] * w[e] * dinv[d];
    }
}

// ---------------- CSR gather (bf16 in, f32 accum, bf16 out) ----------------
template <int EPI>
__global__ void agg_bf_k(const int* __restrict__ rp, const int* __restrict__ cs,
                         const float* __restrict__ cn,
                         const unsigned short* __restrict__ X, int ldx2, int xo2,
                         const float* __restrict__ dinv, const float* __restrict__ bias,
                         unsigned short* __restrict__ Y, int ldy2, int yo2, int N) {
    int wid = (blockIdx.x * blockDim.x + threadIdx.x) >> 6;
    int lane = threadIdx.x & 63;
    if (wid >= N) return;
    const unsigned int* Xu = (const unsigned int*)X;
    float dv = dinv[wid]; dv *= dv;
    unsigned int sv = Xu[(size_t)wid * ldx2 + xo2 + lane];
    float ax = bf2f(sv & 0xffffu) * dv, ay = bf2f(sv >> 16) * dv;
    int p = rp[wid], pe = rp[wid + 1];
    for (; p + 4 <= pe; p += 4) {
        int s0 = cs[p], s1 = cs[p+1], s2 = cs[p+2], s3 = cs[p+3];
        float n0 = cn[p], n1 = cn[p+1], n2 = cn[p+2], n3 = cn[p+3];
        unsigned int v0 = Xu[(size_t)s0 * ldx2 + xo2 + lane];
        unsigned int v1 = Xu[(size_t)s1 * ldx2 + xo2 + lane];
        unsigned int v2 = Xu[(size_t)s2 * ldx2 + xo2 + lane];
        unsigned int v3 = Xu[(size_t)s3 * ldx2 + xo2 + lane];
        ax = fmaf(bf2f(v0 & 0xffffu), n0, ax); ay = fmaf(bf2f(v0 >> 16), n0, ay);
        ax = fmaf(bf2f(v1 & 0xffffu), n1, ax); ay = fmaf(bf2f(v1 >> 16), n1, ay);
        ax = fmaf(bf2f(v2 & 0xffffu), n2, ax); ay = fmaf(bf2f(v2 >> 16), n2, ay);
        ax = fmaf(bf2f(v3 & 0xffffu), n3, ax); ay = fmaf(bf2f(v3 >> 16), n3, ay);
    }
    for (; p < pe; ++p) {
        int s = cs[p]; float nv = cn[p];
        unsigned int v = Xu[(size_t)s * ldx2 + xo2 + lane];
        ax = fmaf(bf2f(v & 0xffffu), nv, ax); ay = fmaf(bf2f(v >> 16), nv, ay);
    }
    if (EPI == 1) {
        ax = fmaxf(ax + bias[lane * 2], 0.f);
        ay = fmaxf(ay + bias[lane * 2 + 1], 0.f);
    }
    ((unsigned int*)Y)[(size_t)wid * ldy2 + yo2 + lane] = pack2(ax, ay);
}

// ---------------- head ----------------

__global__ void colsum_bf_k(const unsigned short* __restrict__ Z, float* zsum, int N) {
    int c = threadIdx.x;
    int rpb = (N + gridDim.x - 1) / gridDim.x;
    int r0 = blockIdx.x * rpb, r1 = min(N, r0 + rpb);
    float s = 0.f;
    for (int r = r0; r < r1; ++r) s += bf2f((unsigned int)Z[(size_t)r * 256 + c]);
    atomicAdd(&zsum[c], s);
}

__global__ void head_k(const float* __restrict__ zsum, const float* __restrict__ Wh,
                       const float* __restrict__ bh, float* __restrict__ out, float invN) {
    __shared__ float red[128];
    int c = threadIdx.x;
    red[c] = zsum[c] * invN * Wh[c];
    __syncthreads();
    for (int s = 64; s > 0; s >>= 1) {
        if (c < s) red[c] += red[c + s];
        __syncthreads();
    }
    if (c == 0) out[0] = red[0] + bh[0];
}

// ---------------- bf16 MFMA GEMM, 128x128 tile, 512 threads (8 waves) ----------------
// 2-phase pipeline, counted vmcnt(2); transposed-acc epilogue (mfma(bfr, af)).
// Wave w: rows wr*32 + ms*16 (+m15), ms=0..1; cols wc*64 + ns*16, ns=0..3.

enum { EPI_G = 0, EPI_P = 1, EPI_ZR = 2, EPI_H = 3 };

__global__ __launch_bounds__(512)
void mm_bf16_k(const unsigned short* __restrict__ A0, const unsigned short* __restrict__ A1,
               int lda0, int lda1, int kb,
               const unsigned short* __restrict__ Bt, int K, int M, int ncb,
               const float* __restrict__ bias,
               const unsigned short* __restrict__ xb1, const unsigned short* __restrict__ xb2,
               void* __restrict__ out, void* __restrict__ out2, int epi)
{
    __shared__ unsigned short Als[2][4096];
    __shared__ unsigned short Bls[2][4096];

    // XCD-bijective swizzle, bcol fast
    int nwg = gridDim.x;
    int bid = blockIdx.x;
    int q = nwg >> 3, r = nwg & 7;
    int xcd = bid & 7;
    int wg = (xcd < r ? xcd * (q + 1) : r * (q + 1) + (xcd - r) * q) + (bid >> 3);
    int brow = wg / ncb, bcol = wg - brow * ncb;
    int row0 = brow * 128, col0 = bcol * 128;

    int t = threadIdx.x;
    int w = t >> 6, lane = t & 63;
    int wr = w >> 1, wc = w & 1;
    int m15 = lane & 15, g = lane >> 4;

    // staging: thread t covers row t>>2 (0..127), swizzled k-slot
    int srow = t >> 2;
    int skk  = (((t & 3) ^ ((t >> 3) & 3)) << 3);

    f32x4 acc[2][4];
    #pragma unroll
    for (int i = 0; i < 2; ++i)
        #pragma unroll
        for (int j = 0; j < 4; ++j)
            #pragma unroll
            for (int qq = 0; qq < 4; ++qq) acc[i][j][qq] = 0.f;

    auto stage = [&](int buf, int kt) {
        const unsigned short* Ap = A0; int lda = lda0; int ka = kt;
        if (kt >= kb) { Ap = A1; lda = lda1; ka = kt - kb; }
        int gr = row0 + srow; gr = gr < M ? gr : M - 1;
        GLOAD_LDS16(&Ap[(size_t)gr * lda + ka + skk], &Als[buf][w * 512]);
        GLOAD_LDS16(&Bt[(size_t)(col0 + srow) * K + kt + skk], &Bls[buf][w * 512]);
    };

    int NT = K >> 5;
    stage(0, 0);
    int pb = 0;

    for (int ti = 0; ti < NT; ++ti) {
        if (ti + 1 < NT) {
            stage(pb ^ 1, (ti + 1) << 5);
            asm volatile("s_waitcnt vmcnt(2)" ::: "memory");
        } else {
            asm volatile("s_waitcnt vmcnt(0)" ::: "memory");
        }
        __builtin_amdgcn_s_barrier();
        __builtin_amdgcn_sched_barrier(0);

        short8 af[2], bfr[4];
        #pragma unroll
        for (int ms = 0; ms < 2; ++ms) {
            int rt = wr * 32 + ms * 16 + m15;
            af[ms] = *(const short8*)&Als[pb][rt * 32 + ((g ^ ((rt >> 1) & 3)) << 3)];
        }
        #pragma unroll
        for (int ns = 0; ns < 4; ++ns) {
            int nt = wc * 64 + ns * 16 + m15;
            bfr[ns] = *(const short8*)&Bls[pb][nt * 32 + ((g ^ ((nt >> 1) & 3)) << 3)];
        }
        asm volatile("s_waitcnt lgkmcnt(0)" ::: "memory");
        __builtin_amdgcn_sched_barrier(0);
        __builtin_amdgcn_s_barrier();

        #pragma unroll
        for (int ms = 0; ms < 2; ++ms)
            #pragma unroll
            for (int ns = 0; ns < 4; ++ns)
                acc[ms][ns] = __builtin_amdgcn_mfma_f32_16x16x32_bf16(bfr[ns], af[ms], acc[ms][ns], 0, 0, 0);
        pb ^= 1;
    }

    // epilogue: row = row0 + wr*32 + ms*16 + m15 ; cols = col0 + wc*64 + ns*16 + g*4 + (0..3)
    #pragma unroll
    for (int ms = 0; ms < 2; ++ms) {
        int row = row0 + wr * 32 + ms * 16 + m15;
        bool rok = row < M;
        #pragma unroll
        for (int ns = 0; ns < 4; ++ns) {
            int col = col0 + wc * 64 + ns * 16 + g * 4;
            f32x4 a = acc[ms][ns];
            if (epi == EPI_G) {
                float4 bv = *(const float4*)&bias[col];
                uint2 p4 = *(const uint2*)&xb1[(size_t)row * 256 + col];
                uint2 o;
                o.x = pack2(fmaxf(a[0] + bv.x, 0.f) + bf2f(p4.x & 0xffffu),
                            fmaxf(a[1] + bv.y, 0.f) + bf2f(p4.x >> 16));
                o.y = pack2(fmaxf(a[2] + bv.z, 0.f) + bf2f(p4.y & 0xffffu),
                            fmaxf(a[3] + bv.w, 0.f) + bf2f(p4.y >> 16));
                if (rok) *(uint2*)&((unsigned short*)out)[(size_t)row * 256 + col] = o;
            } else if (epi == EPI_P) {
                uint2 o;
                o.x = pack2(a[0], a[1]);
                o.y = pack2(a[2], a[3]);
                if (rok) *(uint2*)&((unsigned short*)out)[(size_t)row * 128 + col] = o;
            } else if (epi == EPI_ZR) {
                float4 bv = *(const float4*)&bias[col];
                float s0 = 1.f / (1.f + __expf(-(a[0] + bv.x)));
                float s1 = 1.f / (1.f + __expf(-(a[1] + bv.y)));
                float s2 = 1.f / (1.f + __expf(-(a[2] + bv.z)));
                float s3 = 1.f / (1.f + __expf(-(a[3] + bv.w)));
                if (col < 256) {
                    uint2 o; o.x = pack2(s0, s1); o.y = pack2(s2, s3);
                    if (rok) *(uint2*)&((unsigned short*)out)[(size_t)row * 256 + col] = o;
                } else {
                    int c2 = col - 256;
                    uint2 p4 = *(const uint2*)&xb1[(size_t)row * 256 + c2];
                    uint2 o;
                    o.x = pack2(bf2f(p4.x & 0xffffu) * s0, bf2f(p4.x >> 16) * s1);
                    o.y = pack2(bf2f(p4.y & 0xffffu) * s2, bf2f(p4.y >> 16) * s3);
                    if (rok) *(uint2*)&((unsigned short*)out2)[(size_t)row * 256 + c2] = o;
                }
            } else {  // EPI_H
                float4 bv = *(const float4*)&bias[col];
                uint2 z4 = *(const uint2*)&xb2[(size_t)row * 256 + col];
                uint2 p4 = *(const uint2*)&xb1[(size_t)row * 256 + col];
                float4 o;
                {
                    float s = a[0] + bv.x, e = __expf(2.f * s);
                    float ht = 1.f - 2.f / (e + 1.f);
                    float Zt = bf2f(z4.x & 0xffffu), ph = bf2f(p4.x & 0xffffu);
                    o.x = Zt * ph + (1.f - Zt) * ht;
                }
                {
                    float s = a[1] + bv.y, e = __expf(2.f * s);
                    float ht = 1.f - 2.f / (e + 1.f);
                    float Zt = bf2f(z4.x >> 16), ph = bf2f(p4.x >> 16);
                    o.y = Zt * ph + (1.f - Zt) * ht;
                }
                {
                    float s = a[2] + bv.z, e = __expf(2.f * s);
                    float ht = 1.f - 2.f / (e + 1.f);
                    float Zt = bf2f(z4.y & 0xffffu), ph = bf2f(p4.y & 0xffffu);
                    o.z = Zt * ph + (1.f - Zt) * ht;
                }
                {
                    float s = a[3] + bv.w, e = __expf(2.f * s);
                    float ht = 1.f - 2.f / (e + 1.f);
                    float Zt = bf2f(z4.y >> 16), ph = bf2f(p4.y >> 16);
                    o.w = Zt * ph + (1.f - Zt) * ht;
                }
                if (rok) *(float4*)&((float*)out)[(size_t)row * 256 + col] = o;
            }
        }
    }
}

// ---------------- launch ----------------

extern "C" void kernel_launch(void* const* d_in, const int* in_sizes, int n_in,
                              void* d_out, int out_size, void* d_ws, size_t ws_size,
                              hipStream_t stream) {
    const float* x      = (const float*)d_in[0];
    const int*   ei     = (const int*)d_in[1];
    const float* ew     = (const float*)d_in[2];
    const float* prev_h = (const float*)d_in[3];
    const float* W1  = (const float*)d_in[4];  const float* b1  = (const float*)d_in[5];
    const float* W2  = (const float*)d_in[6];  const float* b2  = (const float*)d_in[7];
    const float* Wxz = (const float*)d_in[8];  const float* bxz = (const float*)d_in[9];
    const float* Whz = (const float*)d_in[10]; const float* bhz = (const float*)d_in[11];
    const float* Wxr = (const float*)d_in[12]; const float* bxr = (const float*)d_in[13];
    const float* Whr = (const float*)d_in[14]; const float* bhr = (const float*)d_in[15];
    const float* Wxh = (const float*)d_in[16]; const float* bxh = (const float*)d_in[17];
    const float* Whh = (const float*)d_in[18]; const float* bhh = (const float*)d_in[19];
    const float* Whead = (const float*)d_in[20]; const float* bhead = (const float*)d_in[21];

    const int N = in_sizes[0] / 128;
    const int E = in_sizes[2];
    const int* esrc = ei;
    const int* edst = ei + E;

    float* ws = (float*)d_ws;
    size_t o = 0;
    float* dinv     = ws + o; o += (size_t)N;
    int*   cnt      = (int*)(ws + o); o += (size_t)N;
    int*   rowp     = (int*)(ws + o); o += (size_t)N + 4;
    int*   bsum     = (int*)(ws + o); o += 256;
    int*   csr_src  = (int*)(ws + o); o += (size_t)E;
    float* csr_norm = ws + o; o += (size_t)E;
    unsigned short* zx   = (unsigned short*)(ws + o); o += (size_t)N * 128;  // [N,256]: z | x
    unsigned short* phb  = (unsigned short*)(ws + o); o += (size_t)N * 128;  // prev_h bf16
    unsigned short* buf1 = (unsigned short*)(ws + o); o += (size_t)N * 128;  // t -> gw2 -> q
    unsigned short* Zbf  = (unsigned short*)(ws + o); o += (size_t)N * 128;  // g_bf -> Z bf16
    unsigned short* Bt1  = (unsigned short*)(ws + o); o += 16384;
    unsigned short* Bt2  = (unsigned short*)(ws + o); o += 16384;
    unsigned short* BtZR = (unsigned short*)(ws + o); o += 131072;
    unsigned short* BtH  = (unsigned short*)(ws + o); o += 65536;
    float* bZR      = ws + o; o += 512;
    float* bH       = ws + o; o += 256;
    float* zsum     = ws + o; o += 128;

    unsigned short* g_bf = Zbf;
    float* hout = (float*)d_out + 1;

    const int TPB = 256;
    int gE = (E + TPB - 1) / TPB;
    int gAgg = (N * 64 + TPB - 1) / TPB;
    int nb = (N + 127) / 128;
    int nsb = (N + 255) / 256;          // scan blocks (must be <= 256)

    // prep: deg/cnt init + x,prev_h -> bf16
    {
        long long tot = (long long)N * 97;
        prep_k<<<(int)((tot + TPB - 1) / TPB), TPB, 0, stream>>>(x, prev_h, dinv, cnt, zx, phb, N);
    }
    // weights + biases: 2*32768 + 6*65536 + 768 = 459520 threads  (r8 bug: was 294912!)
    {
        const int cvtw_total = 2 * 32768 + 6 * 65536 + 768;
        cvtwb_k<<<(cvtw_total + TPB - 1) / TPB, TPB, 0, stream>>>(
            W1, W2, Wxz, Whz, Wxr, Whr, Wxh, Whh,
            bxz, bhz, bxr, bhr, bxh, bhh, Bt1, Bt2, BtZR, BtH, bZR, bH);
    }

    // degree + CSR
    deg_cnt_k<<<gE, TPB, 0, stream>>>(edst, ew, dinv, cnt, E);
    dinv_k<<<(N + TPB - 1) / TPB, TPB, 0, stream>>>(dinv, N);
    scan1_k<<<nsb, 256, 0, stream>>>(cnt, bsum, N);
    scan2_k<<<1, 256, 0, stream>>>(bsum, nsb);
    scan3_k<<<nsb, 256, 0, stream>>>(cnt, bsum, rowp, N);
    fill_csr_k<<<gE, TPB, 0, stream>>>(esrc, edst, ew, dinv, cnt, csr_src, csr_norm, E);

    // t = agg(x)
    agg_bf_k<0><<<gAgg, TPB, 0, stream>>>(rowp, csr_src, csr_norm, zx, 128, 64, dinv,
                                          nullptr, buf1, 64, 0, N);

    // g = relu(t@W1 + b1) + prev_h
    mm_bf16_k<<<nb * 2, 512, 0, stream>>>(buf1, buf1, 128, 128, 128, Bt1, 128, N, 2,
                                          b1, phb, nullptr, g_bf, nullptr, EPI_G);
    // gw2 = g@W2
    mm_bf16_k<<<nb, 512, 0, stream>>>(g_bf, g_bf, 256, 256, 256, Bt2, 256, N, 1,
                                      nullptr, nullptr, nullptr, buf1, nullptr, EPI_P);
    // z = relu(agg(gw2) + b2)
    agg_bf_k<1><<<gAgg, TPB, 0, stream>>>(rowp, csr_src, csr_norm, buf1, 64, 0, dinv,
                                          b2, zx, 128, 0, N);

    // head
    hipMemsetAsync(zsum, 0, 128 * sizeof(float), stream);
    colsum_bf_k<<<512, 128, 0, stream>>>(zx, zsum, N);
    head_k<<<1, 128, 0, stream>>>(zsum, Whead, bhead, (float*)d_out, 1.0f / (float)N);

    // Z|R fused GEMM
    mm_bf16_k<<<nb * 4, 512, 0, stream>>>(zx, phb, 256, 256, 256, BtZR, 512, N, 4,
                                          bZR, phb, nullptr, Zbf, buf1, EPI_ZR);
    // h GEMM
    mm_bf16_k<<<nb * 2, 512, 0, stream>>>(zx, buf1, 256, 256, 256, BtH, 512, N, 2,
                                          bH, phb, Zbf, hout, nullptr, EPI_H);
}